// Round 13
// baseline (174.612 us; speedup 1.0000x reference)
//
#include <hip/hip_runtime.h>
#include <hip/hip_fp16.h>

#define F_IN 20
#define F_HID 64
#define F_OUT 2
#define BKT 256         // nodes per bucket
#define MAXNB 512       // max buckets the LDS arrays support
#define STAGE_MAX 10240 // per-bucket LDS edge staging in kB (= CAP, 40 KB)
#define G8 8            // lanes per node in gather kernels
#define CHUNK 2048      // edges per WG in kA2 (full staging, ~24KB LDS -> 6 WG/CU)
#define PAD 16          // ints per global atomic bin (one 64B line)
#define CAP 10240       // fixed per-bucket region capacity (mean 8184 + 22 sigma)
#define SPILLCAP 32768  // spill list capacity (edges)

// ===================== bucketed capacity path =====================

// init per-bucket cursors to region bases; zero spill counter
__global__ void kinit(int* __restrict__ gcursor, int* __restrict__ spillcnt, int nb) {
    int i = blockIdx.x * blockDim.x + threadIdx.x;
    if (i < nb) gcursor[i * PAD] = i * CAP;
    if (i == 0) spillcnt[0] = 0;
}

// Full-staging LDS-reorder scatter: stage chunk in LDS, local counting sort by
// bucket, claim per-bucket runs, coalesced run writes into capacity regions.
__global__ __launch_bounds__(256) void kA2(const int* __restrict__ src,
                                           const int* __restrict__ dst,
                                           int* __restrict__ gcursor,
                                           int* __restrict__ bedge,
                                           int* __restrict__ spill,
                                           int* __restrict__ spillcnt,
                                           int e, int nb) {
    __shared__ int stage[CHUNK];
    __shared__ unsigned short bkt[CHUNK];
    __shared__ unsigned short inv[CHUNK];
    __shared__ int cnt[MAXNB];
    __shared__ int lbase[MAXNB];
    __shared__ int lcur[MAXNB];
    __shared__ int gclaim[MAXNB];
    __shared__ int wtot[4];
    const int tid = threadIdx.x;
    const int lo = blockIdx.x * CHUNK;
    const int hi = min(e, lo + CHUNK);
    const int cn = hi - lo;
    for (int t = tid; t < MAXNB; t += 256) cnt[t] = 0;
    __syncthreads();
    for (int j = tid; j < cn; j += 256) {
        int d = dst[lo + j], s = src[lo + j];
        int b = d >> 8;
        stage[j] = ((d & (BKT - 1)) << 20) | s;
        bkt[j] = (unsigned short)b;
        atomicAdd(&cnt[b], 1);
    }
    __syncthreads();
    const int t2 = tid * 2;
    int v0 = cnt[t2], v1 = cnt[t2 + 1];
    int pv = v0 + v1;
    int sv = pv;
#pragma unroll
    for (int off = 1; off < 64; off <<= 1) {
        int u = __shfl_up(sv, off, 64);
        if ((tid & 63) >= off) sv += u;
    }
    if ((tid & 63) == 63) wtot[tid >> 6] = sv;
    __syncthreads();
    int wo = 0;
    for (int w = 0; w < (tid >> 6); ++w) wo += wtot[w];
    int excl = wo + sv - pv;
    lbase[t2] = excl;          lcur[t2] = excl;
    lbase[t2 + 1] = excl + v0; lcur[t2 + 1] = excl + v0;
    if (v0 && t2 < nb)     gclaim[t2]     = atomicAdd(&gcursor[t2 * PAD], v0);
    if (v1 && t2 + 1 < nb) gclaim[t2 + 1] = atomicAdd(&gcursor[(t2 + 1) * PAD], v1);
    __syncthreads();
    for (int j = tid; j < cn; j += 256) {
        int p = atomicAdd(&lcur[bkt[j]], 1);
        inv[p] = (unsigned short)j;
    }
    __syncthreads();
    for (int t = tid; t < cn; t += 256) {
        int j = inv[t];
        int b = bkt[j];
        int pos = gclaim[b] + (t - lbase[b]);
        if (pos < (b + 1) * CAP) {
            bedge[pos] = stage[j];
        } else {                             // region overflow -> spill
            int sp = atomicAdd(spillcnt, 1);
            if (sp < SPILLCAP) {
                int w = stage[j];
                spill[2 * sp] = (b << 8) | (((unsigned)w) >> 20);  // full dst
                spill[2 * sp + 1] = w & 1048575;                    // src
            }
        }
    }
}

// per-bucket in-LDS counting sort (in place) -> row_ptr, rcnt (sorted deg), rdeg
__global__ __launch_bounds__(256) void kB(int* __restrict__ bedge,
                                          const int* __restrict__ gcursor,
                                          int* __restrict__ row_ptr,
                                          int* __restrict__ rcnt,
                                          int* __restrict__ rdeg, int n) {
    __shared__ int stage[STAGE_MAX];
    __shared__ int hist[BKT];
    __shared__ int cur[BKT];
    __shared__ int wsum[4];
    const int tid = threadIdx.x, b = blockIdx.x;
    const int lo = b * CAP;
    int cnt = gcursor[b * PAD] - lo;
    if (cnt > CAP) cnt = CAP;
    hist[tid] = 0;
    __syncthreads();
    for (int j = tid; j < cnt; j += 256) {
        int w = bedge[lo + j];
        stage[j] = w;
        atomicAdd(&hist[((unsigned)w) >> 20], 1);
    }
    __syncthreads();
    int v = hist[tid];
    int sv = v;
#pragma unroll
    for (int off = 1; off < 64; off <<= 1) {
        int t = __shfl_up(sv, off, 64);
        if ((tid & 63) >= off) sv += t;
    }
    if ((tid & 63) == 63) wsum[tid >> 6] = sv;
    __syncthreads();
    int wo = 0;
    for (int w = 0; w < (tid >> 6); ++w) wo += wsum[w];
    int excl = wo + sv - v;
    cur[tid] = excl;
    int node = (b << 8) + tid;
    if (node < n) {
        row_ptr[node] = lo + excl;
        rcnt[node] = v;
        rdeg[node] = v;     // corrected by kFix if spill > 0
    }
    __syncthreads();
    for (int j = tid; j < cnt; j += 256) {
        int w = stage[j];
        int pos = atomicAdd(&cur[((unsigned)w) >> 20], 1);
        bedge[lo + pos] = w & 1048575;
    }
}

// fold spilled edges into total degree
__global__ void kFix(const int* __restrict__ spill, const int* __restrict__ spillcnt,
                     int* __restrict__ rdeg) {
    int m = spillcnt[0];
    if (m > SPILLCAP) m = SPILLCAP;
    int stride = gridDim.x * blockDim.x;
    for (int i = blockIdx.x * blockDim.x + threadIdx.x; i < m; i += stride)
        atomicAdd(&rdeg[spill[2 * i]], 1);
}

// split fp16 tables: xhA = feat 0-15, 32B/row aligned (3.2MB, L2-fits);
// xhB = feat 16-19, 8B/row (0.8MB, always L2-resident)
__global__ __launch_bounds__(256) void kxh_s(const float* __restrict__ x,
                                             const int* __restrict__ rdeg,
                                             unsigned* __restrict__ xhA,
                                             unsigned* __restrict__ xhB, int n) {
    int i = blockIdx.x * blockDim.x + threadIdx.x;
    if (i >= n) return;
    float dv = rsqrtf(1.0f + (float)rdeg[i]);
    const float4* xr = (const float4*)(x + (size_t)i * F_IN);
    unsigned w[10];
#pragma unroll
    for (int k = 0; k < 5; ++k) {
        float4 v = xr[k];
        __half2 h0 = __float22half2_rn(make_float2(v.x * dv, v.y * dv));
        __half2 h1 = __float22half2_rn(make_float2(v.z * dv, v.w * dv));
        w[k * 2 + 0] = *(const unsigned*)&h0;
        w[k * 2 + 1] = *(const unsigned*)&h1;
    }
    uint4* oa = (uint4*)(xhA + (size_t)i * 8);
    oa[0] = make_uint4(w[0], w[1], w[2], w[3]);
    oa[1] = make_uint4(w[4], w[5], w[6], w[7]);
    uint2* ob = (uint2*)(xhB + (size_t)i * 2);
    ob[0] = make_uint2(w[8], w[9]);
}

#define ACC2(u, idx) { float2 f_ = __half22float2(*(const __half2*)&(u)); \
                       acc[idx] += f_.x; acc[idx + 1] += f_.y; }

#define GATH1(s) { \
    const uint4* ra_ = (const uint4*)(xhA + (size_t)(s) * 8); \
    uint4 q0_ = ra_[0], q1_ = ra_[1]; \
    uint2 q2_ = *(const uint2*)(xhB + (size_t)(s) * 2); \
    ACC2(q0_.x, 0)  ACC2(q0_.y, 2)  ACC2(q0_.z, 4)  ACC2(q0_.w, 6) \
    ACC2(q1_.x, 8)  ACC2(q1_.y, 10) ACC2(q1_.z, 12) ACC2(q1_.w, 14) \
    ACC2(q2_.x, 16) ACC2(q2_.y, 18) }

// layer-1 single pass over split tables + fused MLP -> ts (8 lanes/node, unroll-4)
__global__ __launch_bounds__(256) void kAgg_s(const int* __restrict__ bedge,
                                              const int* __restrict__ row_ptr,
                                              const int* __restrict__ rcnt,
                                              const int* __restrict__ rdeg,
                                              const int* __restrict__ spill,
                                              const int* __restrict__ spillcnt,
                                              const float* __restrict__ x,
                                              const unsigned* __restrict__ xhA,
                                              const unsigned* __restrict__ xhB,
                                              const float* __restrict__ W1,
                                              const float* __restrict__ b1,
                                              const float* __restrict__ W2,
                                              float* __restrict__ ts, int n) {
    __shared__ float W1s[F_IN * F_HID];
    __shared__ float b1s[F_HID];
    __shared__ float W2s[F_HID * F_OUT];
    for (int t = threadIdx.x; t < F_IN * F_HID; t += 256) W1s[t] = W1[t];
    if (threadIdx.x < F_HID) b1s[threadIdx.x] = b1[threadIdx.x];
    if (threadIdx.x < F_HID * F_OUT) W2s[threadIdx.x] = W2[threadIdx.x];
    __syncthreads();
    const int node = (blockIdx.x * 256 + threadIdx.x) >> 3;
    const int g = threadIdx.x & (G8 - 1);
    if (node >= n) return;
    const float dv = rsqrtf(1.0f + (float)rdeg[node]);
    float acc[F_IN];
#pragma unroll
    for (int k = 0; k < F_IN; ++k) acc[k] = 0.0f;
    {
        int jb = row_ptr[node], je = jb + rcnt[node];
        int j = jb + g;
        for (; j + 3 * G8 < je; j += 4 * G8) {   // unroll-4: 4 independent chains
            int s0 = __builtin_nontemporal_load(&bedge[j]);
            int s1 = __builtin_nontemporal_load(&bedge[j + G8]);
            int s2 = __builtin_nontemporal_load(&bedge[j + 2 * G8]);
            int s3 = __builtin_nontemporal_load(&bedge[j + 3 * G8]);
            GATH1(s0)
            GATH1(s1)
            GATH1(s2)
            GATH1(s3)
        }
        for (; j < je; j += G8) {
            int s0 = __builtin_nontemporal_load(&bedge[j]);
            GATH1(s0)
        }
    }
    {   // spilled edges (normally zero)
        int m = spillcnt[0];
        if (m > SPILLCAP) m = SPILLCAP;
        for (int i = g; i < m; i += G8) {
            if (spill[2 * i] == node) {
                int s0 = spill[2 * i + 1];
                GATH1(s0)
            }
        }
    }
    if (g == 0) {  // self-loop term exact fp32: x[node]*dv
        const float4* xr = (const float4*)(x + (size_t)node * F_IN);
#pragma unroll
        for (int k = 0; k < 5; ++k) {
            float4 vv = xr[k];
            acc[k * 4 + 0] = fmaf(vv.x, dv, acc[k * 4 + 0]);
            acc[k * 4 + 1] = fmaf(vv.y, dv, acc[k * 4 + 1]);
            acc[k * 4 + 2] = fmaf(vv.z, dv, acc[k * 4 + 2]);
            acc[k * 4 + 3] = fmaf(vv.w, dv, acc[k * 4 + 3]);
        }
    }
#pragma unroll
    for (int k = 0; k < F_IN; ++k) {
        acc[k] += __shfl_xor(acc[k], 1, 64);
        acc[k] += __shfl_xor(acc[k], 2, 64);
        acc[k] += __shfl_xor(acc[k], 4, 64);
        acc[k] *= dv;
    }
    float t0 = 0.0f, t1 = 0.0f;  // lane g: hidden units [g*8, g*8+8)
#pragma unroll
    for (int jj = 0; jj < 8; ++jj) {
        int j = g * 8 + jj;
        float a = b1s[j];
#pragma unroll
        for (int k = 0; k < F_IN; ++k) a = fmaf(acc[k], W1s[k * F_HID + j], a);
        float h = fmaxf(a, 0.0f);
        t0 = fmaf(h, W2s[j * F_OUT + 0], t0);
        t1 = fmaf(h, W2s[j * F_OUT + 1], t1);
    }
    t0 += __shfl_xor(t0, 1, 64); t0 += __shfl_xor(t0, 2, 64); t0 += __shfl_xor(t0, 4, 64);
    t1 += __shfl_xor(t1, 1, 64); t1 += __shfl_xor(t1, 2, 64); t1 += __shfl_xor(t1, 4, 64);
    if (g == 0) *(float2*)(ts + (size_t)node * 2) = make_float2(t0 * dv, t1 * dv);
}

// layer-2: 8-lane-per-node gather of ts -> out (unroll-4)
__global__ __launch_bounds__(256) void kL2g(const int* __restrict__ bedge,
                                            const int* __restrict__ row_ptr,
                                            const int* __restrict__ rcnt,
                                            const int* __restrict__ rdeg,
                                            const int* __restrict__ spill,
                                            const int* __restrict__ spillcnt,
                                            const float* __restrict__ ts,
                                            const float* __restrict__ b2,
                                            float* __restrict__ out, int n) {
    const int node = (blockIdx.x * 256 + threadIdx.x) >> 3;
    const int g = threadIdx.x & (G8 - 1);
    if (node >= n) return;
    float a0 = 0.0f, a1 = 0.0f;
    {
        int jb = row_ptr[node], je = jb + rcnt[node];
        int j = jb + g;
        for (; j + 3 * G8 < je; j += 4 * G8) {
            int s0 = __builtin_nontemporal_load(&bedge[j]);
            int s1 = __builtin_nontemporal_load(&bedge[j + G8]);
            int s2 = __builtin_nontemporal_load(&bedge[j + 2 * G8]);
            int s3 = __builtin_nontemporal_load(&bedge[j + 3 * G8]);
            float2 u0 = *(const float2*)(ts + (size_t)s0 * 2);
            float2 u1 = *(const float2*)(ts + (size_t)s1 * 2);
            float2 u2 = *(const float2*)(ts + (size_t)s2 * 2);
            float2 u3 = *(const float2*)(ts + (size_t)s3 * 2);
            a0 += u0.x + u1.x + u2.x + u3.x;
            a1 += u0.y + u1.y + u2.y + u3.y;
        }
        for (; j < je; j += G8) {
            int s0 = __builtin_nontemporal_load(&bedge[j]);
            float2 u0 = *(const float2*)(ts + (size_t)s0 * 2);
            a0 += u0.x; a1 += u0.y;
        }
    }
    {   // spilled edges (normally zero)
        int m = spillcnt[0];
        if (m > SPILLCAP) m = SPILLCAP;
        for (int i = g; i < m; i += G8) {
            if (spill[2 * i] == node) {
                float2 u = *(const float2*)(ts + (size_t)spill[2 * i + 1] * 2);
                a0 += u.x; a1 += u.y;
            }
        }
    }
    a0 += __shfl_xor(a0, 1, 64); a0 += __shfl_xor(a0, 2, 64); a0 += __shfl_xor(a0, 4, 64);
    a1 += __shfl_xor(a1, 1, 64); a1 += __shfl_xor(a1, 2, 64); a1 += __shfl_xor(a1, 4, 64);
    if (g == 0) {
        float dv = rsqrtf(1.0f + (float)rdeg[node]);
        float2 t = *(const float2*)(ts + (size_t)node * 2);
        *(float2*)(out + (size_t)node * 2) =
            make_float2(b2[0] + (a0 + t.x) * dv, b2[1] + (a1 + t.y) * dv);
    }
}

// ===================== fallback: CSR path =====================

__global__ void k_zero_i(int* __restrict__ p, int n) {
    int i = blockIdx.x * blockDim.x + threadIdx.x;
    if (i < n) p[i] = 0;
}
__global__ void k_hist(const int* __restrict__ dst, int* __restrict__ counts, int e) {
    int i = blockIdx.x * blockDim.x + threadIdx.x;
    if (i < e) atomicAdd(&counts[dst[i]], 1);
}
__global__ __launch_bounds__(1024) void k_scan(const int* __restrict__ counts,
                                               int* __restrict__ row_ptr,
                                               int* __restrict__ cursor, int n) {
    __shared__ int warp_sums[16];
    __shared__ int carry_s;
    const int tid = threadIdx.x;
    const int lane = tid & 63, wid = tid >> 6;
    if (tid == 0) carry_s = 0;
    __syncthreads();
    for (int base = 0; base < n; base += 1024) {
        int i = base + tid;
        int v = (i < n) ? counts[i] : 0;
        int sv = v;
#pragma unroll
        for (int off = 1; off < 64; off <<= 1) {
            int t = __shfl_up(sv, off, 64);
            if (lane >= off) sv += t;
        }
        if (lane == 63) warp_sums[wid] = sv;
        __syncthreads();
        if (wid == 0 && lane < 16) {
            int ws = warp_sums[lane];
#pragma unroll
            for (int off = 1; off < 16; off <<= 1) {
                int t = __shfl_up(ws, off, 16);
                if (lane >= off) ws += t;
            }
            warp_sums[lane] = ws;
        }
        __syncthreads();
        int wofs = (wid > 0) ? warp_sums[wid - 1] : 0;
        int excl = carry_s + wofs + sv - v;
        if (i < n) { row_ptr[i] = excl; cursor[i] = excl; }
        __syncthreads();
        if (tid == 0) carry_s += warp_sums[15];
        __syncthreads();
    }
    if (tid == 0) row_ptr[n] = carry_s;
}
__global__ void k_fill(const int* __restrict__ src, const int* __restrict__ dst,
                       int* __restrict__ cursor, int* __restrict__ edge_src, int e) {
    int i = blockIdx.x * blockDim.x + threadIdx.x;
    if (i >= e) return;
    int s = src[i], d = dst[i];
    int pos = atomicAdd(&cursor[d], 1);
    edge_src[pos] = s;
}
__global__ void k_dinv_fb(const int* __restrict__ counts, float* __restrict__ dinv, int n) {
    int i = blockIdx.x * blockDim.x + threadIdx.x;
    if (i < n) dinv[i] = rsqrtf(1.0f + (float)counts[i]);
}
__global__ void k_gather_mlp(const int* __restrict__ row_ptr, const int* __restrict__ edge_src,
                             const float* __restrict__ x, const float* __restrict__ dinv,
                             const float* __restrict__ W1, const float* __restrict__ b1,
                             const float* __restrict__ W2, float* __restrict__ ts, int n) {
    __shared__ float W1s[F_IN * F_HID];
    __shared__ float b1s[F_HID];
    __shared__ float W2s[F_HID * F_OUT];
    for (int t = threadIdx.x; t < F_IN * F_HID; t += blockDim.x) W1s[t] = W1[t];
    if (threadIdx.x < F_HID) b1s[threadIdx.x] = b1[threadIdx.x];
    if (threadIdx.x < F_HID * F_OUT) W2s[threadIdx.x] = W2[threadIdx.x];
    __syncthreads();
    int i = blockIdx.x * blockDim.x + threadIdx.x;
    if (i >= n) return;
    float dv = dinv[i];
    float acc[F_IN];
    {
        float d2 = dv * dv;
        const float4* xr = (const float4*)(x + (size_t)i * F_IN);
#pragma unroll
        for (int k = 0; k < 5; ++k) {
            float4 v = xr[k];
            acc[k * 4 + 0] = v.x * d2; acc[k * 4 + 1] = v.y * d2;
            acc[k * 4 + 2] = v.z * d2; acc[k * 4 + 3] = v.w * d2;
        }
    }
    int jb = row_ptr[i], je = row_ptr[i + 1];
    for (int j = jb; j < je; ++j) {
        int s = edge_src[j];
        float w = dinv[s] * dv;
        const float4* xr = (const float4*)(x + (size_t)s * F_IN);
#pragma unroll
        for (int k = 0; k < 5; ++k) {
            float4 v = xr[k];
            acc[k * 4 + 0] = fmaf(v.x, w, acc[k * 4 + 0]);
            acc[k * 4 + 1] = fmaf(v.y, w, acc[k * 4 + 1]);
            acc[k * 4 + 2] = fmaf(v.z, w, acc[k * 4 + 2]);
            acc[k * 4 + 3] = fmaf(v.w, w, acc[k * 4 + 3]);
        }
    }
    float t0 = 0.0f, t1 = 0.0f;
#pragma unroll 8
    for (int j = 0; j < F_HID; ++j) {
        float a = b1s[j];
#pragma unroll
        for (int k = 0; k < F_IN; ++k) a = fmaf(acc[k], W1s[k * F_HID + j], a);
        float h = fmaxf(a, 0.0f);
        t0 = fmaf(h, W2s[j * F_OUT + 0], t0);
        t1 = fmaf(h, W2s[j * F_OUT + 1], t1);
    }
    ts[(size_t)i * 2 + 0] = t0 * dv;
    ts[(size_t)i * 2 + 1] = t1 * dv;
}
__global__ void k_gather2(const int* __restrict__ row_ptr, const int* __restrict__ edge_src,
                          const float* __restrict__ ts, const float* __restrict__ dinv,
                          const float* __restrict__ b2, float* __restrict__ out, int n) {
    int i = blockIdx.x * blockDim.x + threadIdx.x;
    if (i >= n) return;
    float dv = dinv[i];
    float2 t = *(const float2*)(ts + (size_t)i * 2);
    float a0 = t.x, a1 = t.y;
    int jb = row_ptr[i], je = row_ptr[i + 1];
    for (int j = jb; j < je; ++j) {
        int s = edge_src[j];
        float2 v = *(const float2*)(ts + (size_t)s * 2);
        a0 += v.x; a1 += v.y;
    }
    out[(size_t)i * 2 + 0] = b2[0] + a0 * dv;
    out[(size_t)i * 2 + 1] = b2[1] + a1 * dv;
}

// ============================ launch ============================

extern "C" void kernel_launch(void* const* d_in, const int* in_sizes, int n_in,
                              void* d_out, int out_size, void* d_ws, size_t ws_size,
                              hipStream_t stream) {
    const float* x  = (const float*)d_in[0];
    const int*   ei = (const int*)d_in[1];
    const float* W1 = (const float*)d_in[2];
    const float* b1 = (const float*)d_in[3];
    const float* W2 = (const float*)d_in[4];
    const float* b2 = (const float*)d_in[5];
    float* out = (float*)d_out;

    const int n = in_sizes[0] / F_IN;
    const int e = in_sizes[1] / 2;
    const int* src = ei;
    const int* dst = ei + e;

    const int B = 256;
    const int gn = (n + B - 1) / B;
    const int ge = (e + B - 1) / B;

    const int NB = (n + BKT - 1) / BKT;
    // layout (words): gcursor NB*PAD | spillcnt PAD | spill 2*SPILLCAP | bedge NB*CAP
    //                 | row_ptr n | rcnt n | rdeg n | ts 2n | [align16] xhA 8n | xhB 2n
    size_t base_words = (size_t)NB * PAD + PAD + 2 * (size_t)SPILLCAP
                      + (size_t)NB * CAP + 5 * (size_t)n;
    size_t xh_off_words = (base_words + 3) & ~(size_t)3;
    size_t need_cap = xh_off_words * 4 + (size_t)n * 40;
    bool cap_ok = ((size_t)NB * CAP >= (size_t)e + NB) && (CAP <= STAGE_MAX);

    if (n < (1 << 20) && NB <= MAXNB && cap_ok && ws_size >= need_cap) {
        int*   gcursor  = (int*)d_ws;                      // NB*PAD
        int*   spillcnt = gcursor + (size_t)NB * PAD;      // PAD
        int*   spill    = spillcnt + PAD;                  // 2*SPILLCAP
        int*   bedge    = spill + 2 * (size_t)SPILLCAP;    // NB*CAP
        int*   row_ptr  = bedge + (size_t)NB * CAP;        // n
        int*   rcnt     = row_ptr + n;                     // n
        int*   rdeg     = rcnt + n;                        // n
        float* ts       = (float*)(rdeg + n);              // 2n
        unsigned* xhA   = (unsigned*)((int*)d_ws + xh_off_words);  // 8n
        unsigned* xhB   = xhA + (size_t)n * 8;                     // 2n

        kinit<<<(NB + 255) / 256, 256, 0, stream>>>(gcursor, spillcnt, NB);
        kA2<<<(e + CHUNK - 1) / CHUNK, 256, 0, stream>>>(src, dst, gcursor, bedge,
                                                         spill, spillcnt, e, NB);
        kB<<<NB, 256, 0, stream>>>(bedge, gcursor, row_ptr, rcnt, rdeg, n);
        kFix<<<16, 256, 0, stream>>>(spill, spillcnt, rdeg);
        kxh_s<<<gn, B, 0, stream>>>(x, rdeg, xhA, xhB, n);
        int gg8 = ((size_t)n * G8 + 255) / 256;
        kAgg_s<<<gg8, 256, 0, stream>>>(bedge, row_ptr, rcnt, rdeg, spill, spillcnt,
                                        x, xhA, xhB, W1, b1, W2, ts, n);
        kL2g<<<gg8, 256, 0, stream>>>(bedge, row_ptr, rcnt, rdeg, spill, spillcnt,
                                      ts, b2, out, n);
    } else {
        int*   counts   = (int*)d_ws;
        int*   row_ptr  = counts + n;
        int*   cursor   = row_ptr + n + 1;
        int*   edge_src = cursor + n;
        float* dinv     = (float*)(edge_src + e);
        float* ts       = dinv + n;

        k_zero_i<<<gn, B, 0, stream>>>(counts, n);
        k_hist<<<ge, B, 0, stream>>>(dst, counts, e);
        k_scan<<<1, 1024, 0, stream>>>(counts, row_ptr, cursor, n);
        k_fill<<<ge, B, 0, stream>>>(src, dst, cursor, edge_src, e);
        k_dinv_fb<<<gn, B, 0, stream>>>(counts, dinv, n);
        k_gather_mlp<<<gn, B, 0, stream>>>(row_ptr, edge_src, x, dinv, W1, b1, W2, ts, n);
        k_gather2<<<gn, B, 0, stream>>>(row_ptr, edge_src, ts, dinv, b2, out, n);
    }
}

// Round 14
// 154.931 us; speedup vs baseline: 1.1270x; 1.1270x over previous
//
#include <hip/hip_runtime.h>
#include <hip/hip_fp16.h>

#define F_IN 20
#define F_HID 64
#define F_OUT 2
#define BKT 256         // nodes per bucket
#define MAXNB 512       // max buckets the LDS arrays support
#define STAGE_MAX 10240 // per-bucket LDS edge staging in kB (= CAP, 40 KB)
#define G16 16          // lanes per node in gather kernels (TLP over ILP)
#define CHUNK 4096      // edges per WG in kA2 (full staging, round-8/12 proven)
#define PAD 16          // ints per global atomic bin (one 64B line)
#define CAP 10240       // fixed per-bucket region capacity (mean 8184 + 22 sigma)
#define SPILLCAP 32768  // spill list capacity (edges)

// ===================== bucketed capacity path =====================

// init per-bucket cursors to region bases; zero spill counter
__global__ void kinit(int* __restrict__ gcursor, int* __restrict__ spillcnt, int nb) {
    int i = blockIdx.x * blockDim.x + threadIdx.x;
    if (i < nb) gcursor[i * PAD] = i * CAP;
    if (i == 0) spillcnt[0] = 0;
}

// Full-staging LDS-reorder scatter (round-8/12 proven): stage chunk in LDS,
// local counting sort by bucket, claim per-bucket runs, coalesced run writes.
__global__ __launch_bounds__(256) void kA2(const int* __restrict__ src,
                                           const int* __restrict__ dst,
                                           int* __restrict__ gcursor,
                                           int* __restrict__ bedge,
                                           int* __restrict__ spill,
                                           int* __restrict__ spillcnt,
                                           int e, int nb) {
    __shared__ int stage[CHUNK];
    __shared__ unsigned short bkt[CHUNK];
    __shared__ unsigned short inv[CHUNK];
    __shared__ int cnt[MAXNB];
    __shared__ int lbase[MAXNB];
    __shared__ int lcur[MAXNB];
    __shared__ int gclaim[MAXNB];
    __shared__ int wtot[4];
    const int tid = threadIdx.x;
    const int lo = blockIdx.x * CHUNK;
    const int hi = min(e, lo + CHUNK);
    const int cn = hi - lo;
    for (int t = tid; t < MAXNB; t += 256) cnt[t] = 0;
    __syncthreads();
    for (int j = tid; j < cn; j += 256) {
        int d = dst[lo + j], s = src[lo + j];
        int b = d >> 8;
        stage[j] = ((d & (BKT - 1)) << 20) | s;
        bkt[j] = (unsigned short)b;
        atomicAdd(&cnt[b], 1);
    }
    __syncthreads();
    const int t2 = tid * 2;
    int v0 = cnt[t2], v1 = cnt[t2 + 1];
    int pv = v0 + v1;
    int sv = pv;
#pragma unroll
    for (int off = 1; off < 64; off <<= 1) {
        int u = __shfl_up(sv, off, 64);
        if ((tid & 63) >= off) sv += u;
    }
    if ((tid & 63) == 63) wtot[tid >> 6] = sv;
    __syncthreads();
    int wo = 0;
    for (int w = 0; w < (tid >> 6); ++w) wo += wtot[w];
    int excl = wo + sv - pv;
    lbase[t2] = excl;          lcur[t2] = excl;
    lbase[t2 + 1] = excl + v0; lcur[t2 + 1] = excl + v0;
    if (v0 && t2 < nb)     gclaim[t2]     = atomicAdd(&gcursor[t2 * PAD], v0);
    if (v1 && t2 + 1 < nb) gclaim[t2 + 1] = atomicAdd(&gcursor[(t2 + 1) * PAD], v1);
    __syncthreads();
    for (int j = tid; j < cn; j += 256) {
        int p = atomicAdd(&lcur[bkt[j]], 1);
        inv[p] = (unsigned short)j;
    }
    __syncthreads();
    for (int t = tid; t < cn; t += 256) {
        int j = inv[t];
        int b = bkt[j];
        int pos = gclaim[b] + (t - lbase[b]);
        if (pos < (b + 1) * CAP) {
            bedge[pos] = stage[j];
        } else {                             // region overflow -> spill
            int sp = atomicAdd(spillcnt, 1);
            if (sp < SPILLCAP) {
                int w = stage[j];
                spill[2 * sp] = (b << 8) | (((unsigned)w) >> 20);  // full dst
                spill[2 * sp + 1] = w & 1048575;                    // src
            }
        }
    }
}

// per-bucket in-LDS counting sort (in place) -> row_ptr, rcnt (sorted deg), rdeg
__global__ __launch_bounds__(256) void kB(int* __restrict__ bedge,
                                          const int* __restrict__ gcursor,
                                          int* __restrict__ row_ptr,
                                          int* __restrict__ rcnt,
                                          int* __restrict__ rdeg, int n) {
    __shared__ int stage[STAGE_MAX];
    __shared__ int hist[BKT];
    __shared__ int cur[BKT];
    __shared__ int wsum[4];
    const int tid = threadIdx.x, b = blockIdx.x;
    const int lo = b * CAP;
    int cnt = gcursor[b * PAD] - lo;
    if (cnt > CAP) cnt = CAP;
    hist[tid] = 0;
    __syncthreads();
    for (int j = tid; j < cnt; j += 256) {
        int w = bedge[lo + j];
        stage[j] = w;
        atomicAdd(&hist[((unsigned)w) >> 20], 1);
    }
    __syncthreads();
    int v = hist[tid];
    int sv = v;
#pragma unroll
    for (int off = 1; off < 64; off <<= 1) {
        int t = __shfl_up(sv, off, 64);
        if ((tid & 63) >= off) sv += t;
    }
    if ((tid & 63) == 63) wsum[tid >> 6] = sv;
    __syncthreads();
    int wo = 0;
    for (int w = 0; w < (tid >> 6); ++w) wo += wsum[w];
    int excl = wo + sv - v;
    cur[tid] = excl;
    int node = (b << 8) + tid;
    if (node < n) {
        row_ptr[node] = lo + excl;
        rcnt[node] = v;
        rdeg[node] = v;     // corrected by kFix if spill > 0
    }
    __syncthreads();
    for (int j = tid; j < cnt; j += 256) {
        int w = stage[j];
        int pos = atomicAdd(&cur[((unsigned)w) >> 20], 1);
        bedge[lo + pos] = w & 1048575;
    }
}

// fold spilled edges into total degree
__global__ void kFix(const int* __restrict__ spill, const int* __restrict__ spillcnt,
                     int* __restrict__ rdeg) {
    int m = spillcnt[0];
    if (m > SPILLCAP) m = SPILLCAP;
    int stride = gridDim.x * blockDim.x;
    for (int i = blockIdx.x * blockDim.x + threadIdx.x; i < m; i += stride)
        atomicAdd(&rdeg[spill[2 * i]], 1);
}

// split fp16 tables: xhA = feat 0-15, 32B/row aligned (3.2MB, L2-fits);
// xhB = feat 16-19, 8B/row (0.8MB, always L2-resident)
__global__ __launch_bounds__(256) void kxh_s(const float* __restrict__ x,
                                             const int* __restrict__ rdeg,
                                             unsigned* __restrict__ xhA,
                                             unsigned* __restrict__ xhB, int n) {
    int i = blockIdx.x * blockDim.x + threadIdx.x;
    if (i >= n) return;
    float dv = rsqrtf(1.0f + (float)rdeg[i]);
    const float4* xr = (const float4*)(x + (size_t)i * F_IN);
    unsigned w[10];
#pragma unroll
    for (int k = 0; k < 5; ++k) {
        float4 v = xr[k];
        __half2 h0 = __float22half2_rn(make_float2(v.x * dv, v.y * dv));
        __half2 h1 = __float22half2_rn(make_float2(v.z * dv, v.w * dv));
        w[k * 2 + 0] = *(const unsigned*)&h0;
        w[k * 2 + 1] = *(const unsigned*)&h1;
    }
    uint4* oa = (uint4*)(xhA + (size_t)i * 8);
    oa[0] = make_uint4(w[0], w[1], w[2], w[3]);
    oa[1] = make_uint4(w[4], w[5], w[6], w[7]);
    uint2* ob = (uint2*)(xhB + (size_t)i * 2);
    ob[0] = make_uint2(w[8], w[9]);
}

#define ACC2(u, idx) { float2 f_ = __half22float2(*(const __half2*)&(u)); \
                       acc[idx] += f_.x; acc[idx + 1] += f_.y; }

#define GATH1(s) { \
    const uint4* ra_ = (const uint4*)(xhA + (size_t)(s) * 8); \
    uint4 q0_ = ra_[0], q1_ = ra_[1]; \
    uint2 q2_ = *(const uint2*)(xhB + (size_t)(s) * 2); \
    ACC2(q0_.x, 0)  ACC2(q0_.y, 2)  ACC2(q0_.z, 4)  ACC2(q0_.w, 6) \
    ACC2(q1_.x, 8)  ACC2(q1_.y, 10) ACC2(q1_.z, 12) ACC2(q1_.w, 14) \
    ACC2(q2_.x, 16) ACC2(q2_.y, 18) }

// layer-1 single pass over split tables + fused MLP -> ts (16 lanes/node, unroll-2)
__global__ __launch_bounds__(256) void kAgg_s(const int* __restrict__ bedge,
                                              const int* __restrict__ row_ptr,
                                              const int* __restrict__ rcnt,
                                              const int* __restrict__ rdeg,
                                              const int* __restrict__ spill,
                                              const int* __restrict__ spillcnt,
                                              const float* __restrict__ x,
                                              const unsigned* __restrict__ xhA,
                                              const unsigned* __restrict__ xhB,
                                              const float* __restrict__ W1,
                                              const float* __restrict__ b1,
                                              const float* __restrict__ W2,
                                              float* __restrict__ ts, int n) {
    __shared__ float W1s[F_IN * F_HID];
    __shared__ float b1s[F_HID];
    __shared__ float W2s[F_HID * F_OUT];
    for (int t = threadIdx.x; t < F_IN * F_HID; t += 256) W1s[t] = W1[t];
    if (threadIdx.x < F_HID) b1s[threadIdx.x] = b1[threadIdx.x];
    if (threadIdx.x < F_HID * F_OUT) W2s[threadIdx.x] = W2[threadIdx.x];
    __syncthreads();
    const int node = (blockIdx.x * 256 + threadIdx.x) >> 4;
    const int g = threadIdx.x & (G16 - 1);
    if (node >= n) return;
    const float dv = rsqrtf(1.0f + (float)rdeg[node]);
    float acc[F_IN];
#pragma unroll
    for (int k = 0; k < F_IN; ++k) acc[k] = 0.0f;
    {
        int jb = row_ptr[node], je = jb + rcnt[node];
        int j = jb + g;
        for (; j + G16 < je; j += 2 * G16) {   // unroll-2: two independent chains
            int s0 = __builtin_nontemporal_load(&bedge[j]);
            int s1 = __builtin_nontemporal_load(&bedge[j + G16]);
            GATH1(s0)
            GATH1(s1)
        }
        if (j < je) {
            int s0 = __builtin_nontemporal_load(&bedge[j]);
            GATH1(s0)
        }
    }
    {   // spilled edges (normally zero)
        int m = spillcnt[0];
        if (m > SPILLCAP) m = SPILLCAP;
        for (int i = g; i < m; i += G16) {
            if (spill[2 * i] == node) {
                int s0 = spill[2 * i + 1];
                GATH1(s0)
            }
        }
    }
    if (g == 0) {  // self-loop term exact fp32: x[node]*dv
        const float4* xr = (const float4*)(x + (size_t)node * F_IN);
#pragma unroll
        for (int k = 0; k < 5; ++k) {
            float4 vv = xr[k];
            acc[k * 4 + 0] = fmaf(vv.x, dv, acc[k * 4 + 0]);
            acc[k * 4 + 1] = fmaf(vv.y, dv, acc[k * 4 + 1]);
            acc[k * 4 + 2] = fmaf(vv.z, dv, acc[k * 4 + 2]);
            acc[k * 4 + 3] = fmaf(vv.w, dv, acc[k * 4 + 3]);
        }
    }
#pragma unroll
    for (int k = 0; k < F_IN; ++k) {
        acc[k] += __shfl_xor(acc[k], 1, 64);
        acc[k] += __shfl_xor(acc[k], 2, 64);
        acc[k] += __shfl_xor(acc[k], 4, 64);
        acc[k] += __shfl_xor(acc[k], 8, 64);
        acc[k] *= dv;
    }
    float t0 = 0.0f, t1 = 0.0f;  // lane g: hidden units [g*4, g*4+4)
#pragma unroll
    for (int jj = 0; jj < 4; ++jj) {
        int j = g * 4 + jj;
        float a = b1s[j];
#pragma unroll
        for (int k = 0; k < F_IN; ++k) a = fmaf(acc[k], W1s[k * F_HID + j], a);
        float h = fmaxf(a, 0.0f);
        t0 = fmaf(h, W2s[j * F_OUT + 0], t0);
        t1 = fmaf(h, W2s[j * F_OUT + 1], t1);
    }
    t0 += __shfl_xor(t0, 1, 64); t0 += __shfl_xor(t0, 2, 64);
    t0 += __shfl_xor(t0, 4, 64); t0 += __shfl_xor(t0, 8, 64);
    t1 += __shfl_xor(t1, 1, 64); t1 += __shfl_xor(t1, 2, 64);
    t1 += __shfl_xor(t1, 4, 64); t1 += __shfl_xor(t1, 8, 64);
    if (g == 0) *(float2*)(ts + (size_t)node * 2) = make_float2(t0 * dv, t1 * dv);
}

// layer-2: 16-lane-per-node gather of ts -> out (unroll-2)
__global__ __launch_bounds__(256) void kL2g(const int* __restrict__ bedge,
                                            const int* __restrict__ row_ptr,
                                            const int* __restrict__ rcnt,
                                            const int* __restrict__ rdeg,
                                            const int* __restrict__ spill,
                                            const int* __restrict__ spillcnt,
                                            const float* __restrict__ ts,
                                            const float* __restrict__ b2,
                                            float* __restrict__ out, int n) {
    const int node = (blockIdx.x * 256 + threadIdx.x) >> 4;
    const int g = threadIdx.x & (G16 - 1);
    if (node >= n) return;
    float a0 = 0.0f, a1 = 0.0f;
    {
        int jb = row_ptr[node], je = jb + rcnt[node];
        int j = jb + g;
        for (; j + G16 < je; j += 2 * G16) {
            int s0 = __builtin_nontemporal_load(&bedge[j]);
            int s1 = __builtin_nontemporal_load(&bedge[j + G16]);
            float2 u0 = *(const float2*)(ts + (size_t)s0 * 2);
            float2 u1 = *(const float2*)(ts + (size_t)s1 * 2);
            a0 += u0.x + u1.x; a1 += u0.y + u1.y;
        }
        if (j < je) {
            int s0 = __builtin_nontemporal_load(&bedge[j]);
            float2 u0 = *(const float2*)(ts + (size_t)s0 * 2);
            a0 += u0.x; a1 += u0.y;
        }
    }
    {   // spilled edges (normally zero)
        int m = spillcnt[0];
        if (m > SPILLCAP) m = SPILLCAP;
        for (int i = g; i < m; i += G16) {
            if (spill[2 * i] == node) {
                float2 u = *(const float2*)(ts + (size_t)spill[2 * i + 1] * 2);
                a0 += u.x; a1 += u.y;
            }
        }
    }
    a0 += __shfl_xor(a0, 1, 64); a0 += __shfl_xor(a0, 2, 64);
    a0 += __shfl_xor(a0, 4, 64); a0 += __shfl_xor(a0, 8, 64);
    a1 += __shfl_xor(a1, 1, 64); a1 += __shfl_xor(a1, 2, 64);
    a1 += __shfl_xor(a1, 4, 64); a1 += __shfl_xor(a1, 8, 64);
    if (g == 0) {
        float dv = rsqrtf(1.0f + (float)rdeg[node]);
        float2 t = *(const float2*)(ts + (size_t)node * 2);
        *(float2*)(out + (size_t)node * 2) =
            make_float2(b2[0] + (a0 + t.x) * dv, b2[1] + (a1 + t.y) * dv);
    }
}

// ===================== fallback: CSR path =====================

__global__ void k_zero_i(int* __restrict__ p, int n) {
    int i = blockIdx.x * blockDim.x + threadIdx.x;
    if (i < n) p[i] = 0;
}
__global__ void k_hist(const int* __restrict__ dst, int* __restrict__ counts, int e) {
    int i = blockIdx.x * blockDim.x + threadIdx.x;
    if (i < e) atomicAdd(&counts[dst[i]], 1);
}
__global__ __launch_bounds__(1024) void k_scan(const int* __restrict__ counts,
                                               int* __restrict__ row_ptr,
                                               int* __restrict__ cursor, int n) {
    __shared__ int warp_sums[16];
    __shared__ int carry_s;
    const int tid = threadIdx.x;
    const int lane = tid & 63, wid = tid >> 6;
    if (tid == 0) carry_s = 0;
    __syncthreads();
    for (int base = 0; base < n; base += 1024) {
        int i = base + tid;
        int v = (i < n) ? counts[i] : 0;
        int sv = v;
#pragma unroll
        for (int off = 1; off < 64; off <<= 1) {
            int t = __shfl_up(sv, off, 64);
            if (lane >= off) sv += t;
        }
        if (lane == 63) warp_sums[wid] = sv;
        __syncthreads();
        if (wid == 0 && lane < 16) {
            int ws = warp_sums[lane];
#pragma unroll
            for (int off = 1; off < 16; off <<= 1) {
                int t = __shfl_up(ws, off, 16);
                if (lane >= off) ws += t;
            }
            warp_sums[lane] = ws;
        }
        __syncthreads();
        int wofs = (wid > 0) ? warp_sums[wid - 1] : 0;
        int excl = carry_s + wofs + sv - v;
        if (i < n) { row_ptr[i] = excl; cursor[i] = excl; }
        __syncthreads();
        if (tid == 0) carry_s += warp_sums[15];
        __syncthreads();
    }
    if (tid == 0) row_ptr[n] = carry_s;
}
__global__ void k_fill(const int* __restrict__ src, const int* __restrict__ dst,
                       int* __restrict__ cursor, int* __restrict__ edge_src, int e) {
    int i = blockIdx.x * blockDim.x + threadIdx.x;
    if (i >= e) return;
    int s = src[i], d = dst[i];
    int pos = atomicAdd(&cursor[d], 1);
    edge_src[pos] = s;
}
__global__ void k_dinv_fb(const int* __restrict__ counts, float* __restrict__ dinv, int n) {
    int i = blockIdx.x * blockDim.x + threadIdx.x;
    if (i < n) dinv[i] = rsqrtf(1.0f + (float)counts[i]);
}
__global__ void k_gather_mlp(const int* __restrict__ row_ptr, const int* __restrict__ edge_src,
                             const float* __restrict__ x, const float* __restrict__ dinv,
                             const float* __restrict__ W1, const float* __restrict__ b1,
                             const float* __restrict__ W2, float* __restrict__ ts, int n) {
    __shared__ float W1s[F_IN * F_HID];
    __shared__ float b1s[F_HID];
    __shared__ float W2s[F_HID * F_OUT];
    for (int t = threadIdx.x; t < F_IN * F_HID; t += blockDim.x) W1s[t] = W1[t];
    if (threadIdx.x < F_HID) b1s[threadIdx.x] = b1[threadIdx.x];
    if (threadIdx.x < F_HID * F_OUT) W2s[threadIdx.x] = W2[threadIdx.x];
    __syncthreads();
    int i = blockIdx.x * blockDim.x + threadIdx.x;
    if (i >= n) return;
    float dv = dinv[i];
    float acc[F_IN];
    {
        float d2 = dv * dv;
        const float4* xr = (const float4*)(x + (size_t)i * F_IN);
#pragma unroll
        for (int k = 0; k < 5; ++k) {
            float4 v = xr[k];
            acc[k * 4 + 0] = v.x * d2; acc[k * 4 + 1] = v.y * d2;
            acc[k * 4 + 2] = v.z * d2; acc[k * 4 + 3] = v.w * d2;
        }
    }
    int jb = row_ptr[i], je = row_ptr[i + 1];
    for (int j = jb; j < je; ++j) {
        int s = edge_src[j];
        float w = dinv[s] * dv;
        const float4* xr = (const float4*)(x + (size_t)s * F_IN);
#pragma unroll
        for (int k = 0; k < 5; ++k) {
            float4 v = xr[k];
            acc[k * 4 + 0] = fmaf(v.x, w, acc[k * 4 + 0]);
            acc[k * 4 + 1] = fmaf(v.y, w, acc[k * 4 + 1]);
            acc[k * 4 + 2] = fmaf(v.z, w, acc[k * 4 + 2]);
            acc[k * 4 + 3] = fmaf(v.w, w, acc[k * 4 + 3]);
        }
    }
    float t0 = 0.0f, t1 = 0.0f;
#pragma unroll 8
    for (int j = 0; j < F_HID; ++j) {
        float a = b1s[j];
#pragma unroll
        for (int k = 0; k < F_IN; ++k) a = fmaf(acc[k], W1s[k * F_HID + j], a);
        float h = fmaxf(a, 0.0f);
        t0 = fmaf(h, W2s[j * F_OUT + 0], t0);
        t1 = fmaf(h, W2s[j * F_OUT + 1], t1);
    }
    ts[(size_t)i * 2 + 0] = t0 * dv;
    ts[(size_t)i * 2 + 1] = t1 * dv;
}
__global__ void k_gather2(const int* __restrict__ row_ptr, const int* __restrict__ edge_src,
                          const float* __restrict__ ts, const float* __restrict__ dinv,
                          const float* __restrict__ b2, float* __restrict__ out, int n) {
    int i = blockIdx.x * blockDim.x + threadIdx.x;
    if (i >= n) return;
    float dv = dinv[i];
    float2 t = *(const float2*)(ts + (size_t)i * 2);
    float a0 = t.x, a1 = t.y;
    int jb = row_ptr[i], je = row_ptr[i + 1];
    for (int j = jb; j < je; ++j) {
        int s = edge_src[j];
        float2 v = *(const float2*)(ts + (size_t)s * 2);
        a0 += v.x; a1 += v.y;
    }
    out[(size_t)i * 2 + 0] = b2[0] + a0 * dv;
    out[(size_t)i * 2 + 1] = b2[1] + a1 * dv;
}

// ============================ launch ============================

extern "C" void kernel_launch(void* const* d_in, const int* in_sizes, int n_in,
                              void* d_out, int out_size, void* d_ws, size_t ws_size,
                              hipStream_t stream) {
    const float* x  = (const float*)d_in[0];
    const int*   ei = (const int*)d_in[1];
    const float* W1 = (const float*)d_in[2];
    const float* b1 = (const float*)d_in[3];
    const float* W2 = (const float*)d_in[4];
    const float* b2 = (const float*)d_in[5];
    float* out = (float*)d_out;

    const int n = in_sizes[0] / F_IN;
    const int e = in_sizes[1] / 2;
    const int* src = ei;
    const int* dst = ei + e;

    const int B = 256;
    const int gn = (n + B - 1) / B;
    const int ge = (e + B - 1) / B;

    const int NB = (n + BKT - 1) / BKT;
    // layout (words): gcursor NB*PAD | spillcnt PAD | spill 2*SPILLCAP | bedge NB*CAP
    //                 | row_ptr n | rcnt n | rdeg n | ts 2n | [align16] xhA 8n | xhB 2n
    size_t base_words = (size_t)NB * PAD + PAD + 2 * (size_t)SPILLCAP
                      + (size_t)NB * CAP + 5 * (size_t)n;
    size_t xh_off_words = (base_words + 3) & ~(size_t)3;
    size_t need_cap = xh_off_words * 4 + (size_t)n * 40;
    bool cap_ok = ((size_t)NB * CAP >= (size_t)e + NB) && (CAP <= STAGE_MAX);

    if (n < (1 << 20) && NB <= MAXNB && cap_ok && ws_size >= need_cap) {
        int*   gcursor  = (int*)d_ws;                      // NB*PAD
        int*   spillcnt = gcursor + (size_t)NB * PAD;      // PAD
        int*   spill    = spillcnt + PAD;                  // 2*SPILLCAP
        int*   bedge    = spill + 2 * (size_t)SPILLCAP;    // NB*CAP
        int*   row_ptr  = bedge + (size_t)NB * CAP;        // n
        int*   rcnt     = row_ptr + n;                     // n
        int*   rdeg     = rcnt + n;                        // n
        float* ts       = (float*)(rdeg + n);              // 2n
        unsigned* xhA   = (unsigned*)((int*)d_ws + xh_off_words);  // 8n
        unsigned* xhB   = xhA + (size_t)n * 8;                     // 2n

        kinit<<<(NB + 255) / 256, 256, 0, stream>>>(gcursor, spillcnt, NB);
        kA2<<<(e + CHUNK - 1) / CHUNK, 256, 0, stream>>>(src, dst, gcursor, bedge,
                                                         spill, spillcnt, e, NB);
        kB<<<NB, 256, 0, stream>>>(bedge, gcursor, row_ptr, rcnt, rdeg, n);
        kFix<<<16, 256, 0, stream>>>(spill, spillcnt, rdeg);
        kxh_s<<<gn, B, 0, stream>>>(x, rdeg, xhA, xhB, n);
        int gg16 = ((size_t)n * G16 + 255) / 256;
        kAgg_s<<<gg16, 256, 0, stream>>>(bedge, row_ptr, rcnt, rdeg, spill, spillcnt,
                                         x, xhA, xhB, W1, b1, W2, ts, n);
        kL2g<<<gg16, 256, 0, stream>>>(bedge, row_ptr, rcnt, rdeg, spill, spillcnt,
                                       ts, b2, out, n);
    } else {
        int*   counts   = (int*)d_ws;
        int*   row_ptr  = counts + n;
        int*   cursor   = row_ptr + n + 1;
        int*   edge_src = cursor + n;
        float* dinv     = (float*)(edge_src + e);
        float* ts       = dinv + n;

        k_zero_i<<<gn, B, 0, stream>>>(counts, n);
        k_hist<<<ge, B, 0, stream>>>(dst, counts, e);
        k_scan<<<1, 1024, 0, stream>>>(counts, row_ptr, cursor, n);
        k_fill<<<ge, B, 0, stream>>>(src, dst, cursor, edge_src, e);
        k_dinv_fb<<<gn, B, 0, stream>>>(counts, dinv, n);
        k_gather_mlp<<<gn, B, 0, stream>>>(row_ptr, edge_src, x, dinv, W1, b1, W2, ts, n);
        k_gather2<<<gn, B, 0, stream>>>(row_ptr, edge_src, ts, dinv, b2, out, n);
    }
}

// Round 15
// 146.677 us; speedup vs baseline: 1.1905x; 1.0563x over previous
//
#include <hip/hip_runtime.h>
#include <hip/hip_fp16.h>

#define F_IN 20
#define F_HID 64
#define F_OUT 2
#define BKT 256         // nodes per bucket
#define MAXNB 512       // max buckets the LDS arrays support
#define STAGE_MAX 10240 // per-bucket LDS edge staging in kB (= CAP, 40 KB)
#define G16 16          // lanes per node in gather kernels
#define CHUNK 4096      // edges per WG in kA2 (full staging)
#define PAD 16          // ints per global atomic bin (one 64B line)
#define CAP 10240       // fixed per-bucket region capacity (mean 8184 + 22 sigma)
#define SPILLCAP 32768  // spill list capacity (edges)

// ===================== bucketed capacity path =====================

// init per-bucket cursors to region bases; zero spill counter
__global__ void kinit(int* __restrict__ gcursor, int* __restrict__ spillcnt, int nb) {
    int i = blockIdx.x * blockDim.x + threadIdx.x;
    if (i < nb) gcursor[i * PAD] = i * CAP;
    if (i == 0) spillcnt[0] = 0;
}

// Full-staging LDS-reorder scatter, 512 threads/WG: stage chunk in LDS, local
// counting sort by bucket, claim per-bucket runs, coalesced run writes.
__global__ __launch_bounds__(512) void kA2(const int* __restrict__ src,
                                           const int* __restrict__ dst,
                                           int* __restrict__ gcursor,
                                           int* __restrict__ bedge,
                                           int* __restrict__ spill,
                                           int* __restrict__ spillcnt,
                                           int e, int nb) {
    __shared__ int stage[CHUNK];
    __shared__ unsigned short bkt[CHUNK];
    __shared__ unsigned short inv[CHUNK];
    __shared__ int cnt[MAXNB];
    __shared__ int lbase[MAXNB];
    __shared__ int lcur[MAXNB];
    __shared__ int gclaim[MAXNB];
    __shared__ int wtot[8];
    const int tid = threadIdx.x;
    const int lo = blockIdx.x * CHUNK;
    const int hi = min(e, lo + CHUNK);
    const int cn = hi - lo;
    if (tid < MAXNB) cnt[tid] = 0;
    __syncthreads();
    for (int j = tid; j < cn; j += 512) {
        int d = dst[lo + j], s = src[lo + j];
        int b = d >> 8;
        stage[j] = ((d & (BKT - 1)) << 20) | s;
        bkt[j] = (unsigned short)b;
        atomicAdd(&cnt[b], 1);
    }
    __syncthreads();
    // 512-thread exclusive scan, 1 bin/thread
    {
        int v = cnt[tid];
        int sv = v;
#pragma unroll
        for (int off = 1; off < 64; off <<= 1) {
            int u = __shfl_up(sv, off, 64);
            if ((tid & 63) >= off) sv += u;
        }
        if ((tid & 63) == 63) wtot[tid >> 6] = sv;
        __syncthreads();
        int wo = 0;
        for (int w = 0; w < (tid >> 6); ++w) wo += wtot[w];
        int excl = wo + sv - v;
        lbase[tid] = excl;
        lcur[tid] = excl;
        if (v && tid < nb) gclaim[tid] = atomicAdd(&gcursor[tid * PAD], v);
    }
    __syncthreads();
    for (int j = tid; j < cn; j += 512) {
        int p = atomicAdd(&lcur[bkt[j]], 1);
        inv[p] = (unsigned short)j;
    }
    __syncthreads();
    for (int t = tid; t < cn; t += 512) {
        int j = inv[t];
        int b = bkt[j];
        int pos = gclaim[b] + (t - lbase[b]);
        if (pos < (b + 1) * CAP) {
            bedge[pos] = stage[j];
        } else {                             // region overflow -> spill
            int sp = atomicAdd(spillcnt, 1);
            if (sp < SPILLCAP) {
                int w = stage[j];
                spill[2 * sp] = (b << 8) | (((unsigned)w) >> 20);  // full dst
                spill[2 * sp + 1] = w & 1048575;                    // src
            }
        }
    }
}

// per-bucket in-LDS counting sort (in place), 512 threads -> row_ptr, rcnt, rdeg
__global__ __launch_bounds__(512) void kB(int* __restrict__ bedge,
                                          const int* __restrict__ gcursor,
                                          int* __restrict__ row_ptr,
                                          int* __restrict__ rcnt,
                                          int* __restrict__ rdeg, int n) {
    __shared__ int stage[STAGE_MAX];
    __shared__ int hist[BKT];
    __shared__ int cur[BKT];
    __shared__ int wsum[4];
    const int tid = threadIdx.x, b = blockIdx.x;
    const int lo = b * CAP;
    int cnt = gcursor[b * PAD] - lo;
    if (cnt > CAP) cnt = CAP;
    if (tid < BKT) hist[tid] = 0;
    __syncthreads();
    for (int j = tid; j < cnt; j += 512) {
        int w = bedge[lo + j];
        stage[j] = w;
        atomicAdd(&hist[((unsigned)w) >> 20], 1);
    }
    __syncthreads();
    if (tid < BKT) {
        int v = hist[tid];
        int sv = v;
#pragma unroll
        for (int off = 1; off < 64; off <<= 1) {
            int t = __shfl_up(sv, off, 64);
            if ((tid & 63) >= off) sv += t;
        }
        if ((tid & 63) == 63) wsum[tid >> 6] = sv;
        __syncthreads();
        int wo = 0;
        for (int w = 0; w < (tid >> 6); ++w) wo += wsum[w];
        int excl = wo + sv - v;
        cur[tid] = excl;
        int node = (b << 8) + tid;
        if (node < n) {
            row_ptr[node] = lo + excl;
            rcnt[node] = v;
            rdeg[node] = v;     // corrected by kFix if spill > 0
        }
    } else {
        __syncthreads();
    }
    __syncthreads();
    for (int j = tid; j < cnt; j += 512) {
        int w = stage[j];
        int pos = atomicAdd(&cur[((unsigned)w) >> 20], 1);
        bedge[lo + pos] = w & 1048575;
    }
}

// fold spilled edges into total degree
__global__ void kFix(const int* __restrict__ spill, const int* __restrict__ spillcnt,
                     int* __restrict__ rdeg) {
    int m = spillcnt[0];
    if (m > SPILLCAP) m = SPILLCAP;
    int stride = gridDim.x * blockDim.x;
    for (int i = blockIdx.x * blockDim.x + threadIdx.x; i < m; i += stride)
        atomicAdd(&rdeg[spill[2 * i]], 1);
}

// split fp16 tables: xhA = feat 0-15, 32B/row aligned (3.2MB, L2-fits);
// xhB = feat 16-19, 8B/row (0.8MB, always L2-resident)
__global__ __launch_bounds__(256) void kxh_s(const float* __restrict__ x,
                                             const int* __restrict__ rdeg,
                                             unsigned* __restrict__ xhA,
                                             unsigned* __restrict__ xhB, int n) {
    int i = blockIdx.x * blockDim.x + threadIdx.x;
    if (i >= n) return;
    float dv = rsqrtf(1.0f + (float)rdeg[i]);
    const float4* xr = (const float4*)(x + (size_t)i * F_IN);
    unsigned w[10];
#pragma unroll
    for (int k = 0; k < 5; ++k) {
        float4 v = xr[k];
        __half2 h0 = __float22half2_rn(make_float2(v.x * dv, v.y * dv));
        __half2 h1 = __float22half2_rn(make_float2(v.z * dv, v.w * dv));
        w[k * 2 + 0] = *(const unsigned*)&h0;
        w[k * 2 + 1] = *(const unsigned*)&h1;
    }
    uint4* oa = (uint4*)(xhA + (size_t)i * 8);
    oa[0] = make_uint4(w[0], w[1], w[2], w[3]);
    oa[1] = make_uint4(w[4], w[5], w[6], w[7]);
    uint2* ob = (uint2*)(xhB + (size_t)i * 2);
    ob[0] = make_uint2(w[8], w[9]);
}

#define ACC2(u, idx) { float2 f_ = __half22float2(*(const __half2*)&(u)); \
                       acc[idx] += f_.x; acc[idx + 1] += f_.y; }

#define GATH1(s) { \
    const uint4* ra_ = (const uint4*)(xhA + (size_t)(s) * 8); \
    uint4 q0_ = ra_[0], q1_ = ra_[1]; \
    uint2 q2_ = *(const uint2*)(xhB + (size_t)(s) * 2); \
    ACC2(q0_.x, 0)  ACC2(q0_.y, 2)  ACC2(q0_.z, 4)  ACC2(q0_.w, 6) \
    ACC2(q1_.x, 8)  ACC2(q1_.y, 10) ACC2(q1_.z, 12) ACC2(q1_.w, 14) \
    ACC2(q2_.x, 16) ACC2(q2_.y, 18) }

// layer-1 single pass over split tables + fused MLP -> ts (16 lanes/node, unroll-2)
__global__ __launch_bounds__(256) void kAgg_s(const int* __restrict__ bedge,
                                              const int* __restrict__ row_ptr,
                                              const int* __restrict__ rcnt,
                                              const int* __restrict__ rdeg,
                                              const int* __restrict__ spill,
                                              const int* __restrict__ spillcnt,
                                              const float* __restrict__ x,
                                              const unsigned* __restrict__ xhA,
                                              const unsigned* __restrict__ xhB,
                                              const float* __restrict__ W1,
                                              const float* __restrict__ b1,
                                              const float* __restrict__ W2,
                                              float* __restrict__ ts, int n) {
    __shared__ float W1s[F_IN * F_HID];
    __shared__ float b1s[F_HID];
    __shared__ float W2s[F_HID * F_OUT];
    for (int t = threadIdx.x; t < F_IN * F_HID; t += 256) W1s[t] = W1[t];
    if (threadIdx.x < F_HID) b1s[threadIdx.x] = b1[threadIdx.x];
    if (threadIdx.x < F_HID * F_OUT) W2s[threadIdx.x] = W2[threadIdx.x];
    __syncthreads();
    const int node = (blockIdx.x * 256 + threadIdx.x) >> 4;
    const int g = threadIdx.x & (G16 - 1);
    if (node >= n) return;
    const float dv = rsqrtf(1.0f + (float)rdeg[node]);
    float acc[F_IN];
#pragma unroll
    for (int k = 0; k < F_IN; ++k) acc[k] = 0.0f;
    {
        int jb = row_ptr[node], je = jb + rcnt[node];
        int j = jb + g;
        for (; j + G16 < je; j += 2 * G16) {   // unroll-2: two independent chains
            int s0 = __builtin_nontemporal_load(&bedge[j]);
            int s1 = __builtin_nontemporal_load(&bedge[j + G16]);
            GATH1(s0)
            GATH1(s1)
        }
        if (j < je) {
            int s0 = __builtin_nontemporal_load(&bedge[j]);
            GATH1(s0)
        }
    }
    {   // spilled edges (normally zero)
        int m = spillcnt[0];
        if (m > SPILLCAP) m = SPILLCAP;
        for (int i = g; i < m; i += G16) {
            if (spill[2 * i] == node) {
                int s0 = spill[2 * i + 1];
                GATH1(s0)
            }
        }
    }
    if (g == 0) {  // self-loop term exact fp32: x[node]*dv
        const float4* xr = (const float4*)(x + (size_t)node * F_IN);
#pragma unroll
        for (int k = 0; k < 5; ++k) {
            float4 vv = xr[k];
            acc[k * 4 + 0] = fmaf(vv.x, dv, acc[k * 4 + 0]);
            acc[k * 4 + 1] = fmaf(vv.y, dv, acc[k * 4 + 1]);
            acc[k * 4 + 2] = fmaf(vv.z, dv, acc[k * 4 + 2]);
            acc[k * 4 + 3] = fmaf(vv.w, dv, acc[k * 4 + 3]);
        }
    }
#pragma unroll
    for (int k = 0; k < F_IN; ++k) {
        acc[k] += __shfl_xor(acc[k], 1, 64);
        acc[k] += __shfl_xor(acc[k], 2, 64);
        acc[k] += __shfl_xor(acc[k], 4, 64);
        acc[k] += __shfl_xor(acc[k], 8, 64);
        acc[k] *= dv;
    }
    float t0 = 0.0f, t1 = 0.0f;  // lane g: hidden units [g*4, g*4+4)
#pragma unroll
    for (int jj = 0; jj < 4; ++jj) {
        int j = g * 4 + jj;
        float a = b1s[j];
#pragma unroll
        for (int k = 0; k < F_IN; ++k) a = fmaf(acc[k], W1s[k * F_HID + j], a);
        float h = fmaxf(a, 0.0f);
        t0 = fmaf(h, W2s[j * F_OUT + 0], t0);
        t1 = fmaf(h, W2s[j * F_OUT + 1], t1);
    }
    t0 += __shfl_xor(t0, 1, 64); t0 += __shfl_xor(t0, 2, 64);
    t0 += __shfl_xor(t0, 4, 64); t0 += __shfl_xor(t0, 8, 64);
    t1 += __shfl_xor(t1, 1, 64); t1 += __shfl_xor(t1, 2, 64);
    t1 += __shfl_xor(t1, 4, 64); t1 += __shfl_xor(t1, 8, 64);
    if (g == 0) *(float2*)(ts + (size_t)node * 2) = make_float2(t0 * dv, t1 * dv);
}

// layer-2: 16-lane-per-node gather of ts -> out (unroll-2)
__global__ __launch_bounds__(256) void kL2g(const int* __restrict__ bedge,
                                            const int* __restrict__ row_ptr,
                                            const int* __restrict__ rcnt,
                                            const int* __restrict__ rdeg,
                                            const int* __restrict__ spill,
                                            const int* __restrict__ spillcnt,
                                            const float* __restrict__ ts,
                                            const float* __restrict__ b2,
                                            float* __restrict__ out, int n) {
    const int node = (blockIdx.x * 256 + threadIdx.x) >> 4;
    const int g = threadIdx.x & (G16 - 1);
    if (node >= n) return;
    float a0 = 0.0f, a1 = 0.0f;
    {
        int jb = row_ptr[node], je = jb + rcnt[node];
        int j = jb + g;
        for (; j + G16 < je; j += 2 * G16) {
            int s0 = __builtin_nontemporal_load(&bedge[j]);
            int s1 = __builtin_nontemporal_load(&bedge[j + G16]);
            float2 u0 = *(const float2*)(ts + (size_t)s0 * 2);
            float2 u1 = *(const float2*)(ts + (size_t)s1 * 2);
            a0 += u0.x + u1.x; a1 += u0.y + u1.y;
        }
        if (j < je) {
            int s0 = __builtin_nontemporal_load(&bedge[j]);
            float2 u0 = *(const float2*)(ts + (size_t)s0 * 2);
            a0 += u0.x; a1 += u0.y;
        }
    }
    {   // spilled edges (normally zero)
        int m = spillcnt[0];
        if (m > SPILLCAP) m = SPILLCAP;
        for (int i = g; i < m; i += G16) {
            if (spill[2 * i] == node) {
                float2 u = *(const float2*)(ts + (size_t)spill[2 * i + 1] * 2);
                a0 += u.x; a1 += u.y;
            }
        }
    }
    a0 += __shfl_xor(a0, 1, 64); a0 += __shfl_xor(a0, 2, 64);
    a0 += __shfl_xor(a0, 4, 64); a0 += __shfl_xor(a0, 8, 64);
    a1 += __shfl_xor(a1, 1, 64); a1 += __shfl_xor(a1, 2, 64);
    a1 += __shfl_xor(a1, 4, 64); a1 += __shfl_xor(a1, 8, 64);
    if (g == 0) {
        float dv = rsqrtf(1.0f + (float)rdeg[node]);
        float2 t = *(const float2*)(ts + (size_t)node * 2);
        *(float2*)(out + (size_t)node * 2) =
            make_float2(b2[0] + (a0 + t.x) * dv, b2[1] + (a1 + t.y) * dv);
    }
}

// ===================== fallback: CSR path =====================

__global__ void k_zero_i(int* __restrict__ p, int n) {
    int i = blockIdx.x * blockDim.x + threadIdx.x;
    if (i < n) p[i] = 0;
}
__global__ void k_hist(const int* __restrict__ dst, int* __restrict__ counts, int e) {
    int i = blockIdx.x * blockDim.x + threadIdx.x;
    if (i < e) atomicAdd(&counts[dst[i]], 1);
}
__global__ __launch_bounds__(1024) void k_scan(const int* __restrict__ counts,
                                               int* __restrict__ row_ptr,
                                               int* __restrict__ cursor, int n) {
    __shared__ int warp_sums[16];
    __shared__ int carry_s;
    const int tid = threadIdx.x;
    const int lane = tid & 63, wid = tid >> 6;
    if (tid == 0) carry_s = 0;
    __syncthreads();
    for (int base = 0; base < n; base += 1024) {
        int i = base + tid;
        int v = (i < n) ? counts[i] : 0;
        int sv = v;
#pragma unroll
        for (int off = 1; off < 64; off <<= 1) {
            int t = __shfl_up(sv, off, 64);
            if (lane >= off) sv += t;
        }
        if (lane == 63) warp_sums[wid] = sv;
        __syncthreads();
        if (wid == 0 && lane < 16) {
            int ws = warp_sums[lane];
#pragma unroll
            for (int off = 1; off < 16; off <<= 1) {
                int t = __shfl_up(ws, off, 16);
                if (lane >= off) ws += t;
            }
            warp_sums[lane] = ws;
        }
        __syncthreads();
        int wofs = (wid > 0) ? warp_sums[wid - 1] : 0;
        int excl = carry_s + wofs + sv - v;
        if (i < n) { row_ptr[i] = excl; cursor[i] = excl; }
        __syncthreads();
        if (tid == 0) carry_s += warp_sums[15];
        __syncthreads();
    }
    if (tid == 0) row_ptr[n] = carry_s;
}
__global__ void k_fill(const int* __restrict__ src, const int* __restrict__ dst,
                       int* __restrict__ cursor, int* __restrict__ edge_src, int e) {
    int i = blockIdx.x * blockDim.x + threadIdx.x;
    if (i >= e) return;
    int s = src[i], d = dst[i];
    int pos = atomicAdd(&cursor[d], 1);
    edge_src[pos] = s;
}
__global__ void k_dinv_fb(const int* __restrict__ counts, float* __restrict__ dinv, int n) {
    int i = blockIdx.x * blockDim.x + threadIdx.x;
    if (i < n) dinv[i] = rsqrtf(1.0f + (float)counts[i]);
}
__global__ void k_gather_mlp(const int* __restrict__ row_ptr, const int* __restrict__ edge_src,
                             const float* __restrict__ x, const float* __restrict__ dinv,
                             const float* __restrict__ W1, const float* __restrict__ b1,
                             const float* __restrict__ W2, float* __restrict__ ts, int n) {
    __shared__ float W1s[F_IN * F_HID];
    __shared__ float b1s[F_HID];
    __shared__ float W2s[F_HID * F_OUT];
    for (int t = threadIdx.x; t < F_IN * F_HID; t += blockDim.x) W1s[t] = W1[t];
    if (threadIdx.x < F_HID) b1s[threadIdx.x] = b1[threadIdx.x];
    if (threadIdx.x < F_HID * F_OUT) W2s[threadIdx.x] = W2[threadIdx.x];
    __syncthreads();
    int i = blockIdx.x * blockDim.x + threadIdx.x;
    if (i >= n) return;
    float dv = dinv[i];
    float acc[F_IN];
    {
        float d2 = dv * dv;
        const float4* xr = (const float4*)(x + (size_t)i * F_IN);
#pragma unroll
        for (int k = 0; k < 5; ++k) {
            float4 v = xr[k];
            acc[k * 4 + 0] = v.x * d2; acc[k * 4 + 1] = v.y * d2;
            acc[k * 4 + 2] = v.z * d2; acc[k * 4 + 3] = v.w * d2;
        }
    }
    int jb = row_ptr[i], je = row_ptr[i + 1];
    for (int j = jb; j < je; ++j) {
        int s = edge_src[j];
        float w = dinv[s] * dv;
        const float4* xr = (const float4*)(x + (size_t)s * F_IN);
#pragma unroll
        for (int k = 0; k < 5; ++k) {
            float4 v = xr[k];
            acc[k * 4 + 0] = fmaf(v.x, w, acc[k * 4 + 0]);
            acc[k * 4 + 1] = fmaf(v.y, w, acc[k * 4 + 1]);
            acc[k * 4 + 2] = fmaf(v.z, w, acc[k * 4 + 2]);
            acc[k * 4 + 3] = fmaf(v.w, w, acc[k * 4 + 3]);
        }
    }
    float t0 = 0.0f, t1 = 0.0f;
#pragma unroll 8
    for (int j = 0; j < F_HID; ++j) {
        float a = b1s[j];
#pragma unroll
        for (int k = 0; k < F_IN; ++k) a = fmaf(acc[k], W1s[k * F_HID + j], a);
        float h = fmaxf(a, 0.0f);
        t0 = fmaf(h, W2s[j * F_OUT + 0], t0);
        t1 = fmaf(h, W2s[j * F_OUT + 1], t1);
    }
    ts[(size_t)i * 2 + 0] = t0 * dv;
    ts[(size_t)i * 2 + 1] = t1 * dv;
}
__global__ void k_gather2(const int* __restrict__ row_ptr, const int* __restrict__ edge_src,
                          const float* __restrict__ ts, const float* __restrict__ dinv,
                          const float* __restrict__ b2, float* __restrict__ out, int n) {
    int i = blockIdx.x * blockDim.x + threadIdx.x;
    if (i >= n) return;
    float dv = dinv[i];
    float2 t = *(const float2*)(ts + (size_t)i * 2);
    float a0 = t.x, a1 = t.y;
    int jb = row_ptr[i], je = row_ptr[i + 1];
    for (int j = jb; j < je; ++j) {
        int s = edge_src[j];
        float2 v = *(const float2*)(ts + (size_t)s * 2);
        a0 += v.x; a1 += v.y;
    }
    out[(size_t)i * 2 + 0] = b2[0] + a0 * dv;
    out[(size_t)i * 2 + 1] = b2[1] + a1 * dv;
}

// ============================ launch ============================

extern "C" void kernel_launch(void* const* d_in, const int* in_sizes, int n_in,
                              void* d_out, int out_size, void* d_ws, size_t ws_size,
                              hipStream_t stream) {
    const float* x  = (const float*)d_in[0];
    const int*   ei = (const int*)d_in[1];
    const float* W1 = (const float*)d_in[2];
    const float* b1 = (const float*)d_in[3];
    const float* W2 = (const float*)d_in[4];
    const float* b2 = (const float*)d_in[5];
    float* out = (float*)d_out;

    const int n = in_sizes[0] / F_IN;
    const int e = in_sizes[1] / 2;
    const int* src = ei;
    const int* dst = ei + e;

    const int B = 256;
    const int gn = (n + B - 1) / B;
    const int ge = (e + B - 1) / B;

    const int NB = (n + BKT - 1) / BKT;
    // layout (words): gcursor NB*PAD | spillcnt PAD | spill 2*SPILLCAP | bedge NB*CAP
    //                 | row_ptr n | rcnt n | rdeg n | ts 2n | [align16] xhA 8n | xhB 2n
    size_t base_words = (size_t)NB * PAD + PAD + 2 * (size_t)SPILLCAP
                      + (size_t)NB * CAP + 5 * (size_t)n;
    size_t xh_off_words = (base_words + 3) & ~(size_t)3;
    size_t need_cap = xh_off_words * 4 + (size_t)n * 40;
    bool cap_ok = ((size_t)NB * CAP >= (size_t)e + NB) && (CAP <= STAGE_MAX);

    if (n < (1 << 20) && NB <= MAXNB && cap_ok && ws_size >= need_cap) {
        int*   gcursor  = (int*)d_ws;                      // NB*PAD
        int*   spillcnt = gcursor + (size_t)NB * PAD;      // PAD
        int*   spill    = spillcnt + PAD;                  // 2*SPILLCAP
        int*   bedge    = spill + 2 * (size_t)SPILLCAP;    // NB*CAP
        int*   row_ptr  = bedge + (size_t)NB * CAP;        // n
        int*   rcnt     = row_ptr + n;                     // n
        int*   rdeg     = rcnt + n;                        // n
        float* ts       = (float*)(rdeg + n);              // 2n
        unsigned* xhA   = (unsigned*)((int*)d_ws + xh_off_words);  // 8n
        unsigned* xhB   = xhA + (size_t)n * 8;                     // 2n

        kinit<<<(NB + 255) / 256, 256, 0, stream>>>(gcursor, spillcnt, NB);
        kA2<<<(e + CHUNK - 1) / CHUNK, 512, 0, stream>>>(src, dst, gcursor, bedge,
                                                         spill, spillcnt, e, NB);
        kB<<<NB, 512, 0, stream>>>(bedge, gcursor, row_ptr, rcnt, rdeg, n);
        kFix<<<16, 256, 0, stream>>>(spill, spillcnt, rdeg);
        kxh_s<<<gn, B, 0, stream>>>(x, rdeg, xhA, xhB, n);
        int gg16 = ((size_t)n * G16 + 255) / 256;
        kAgg_s<<<gg16, 256, 0, stream>>>(bedge, row_ptr, rcnt, rdeg, spill, spillcnt,
                                         x, xhA, xhB, W1, b1, W2, ts, n);
        kL2g<<<gg16, 256, 0, stream>>>(bedge, row_ptr, rcnt, rdeg, spill, spillcnt,
                                       ts, b2, out, n);
    } else {
        int*   counts   = (int*)d_ws;
        int*   row_ptr  = counts + n;
        int*   cursor   = row_ptr + n + 1;
        int*   edge_src = cursor + n;
        float* dinv     = (float*)(edge_src + e);
        float* ts       = dinv + n;

        k_zero_i<<<gn, B, 0, stream>>>(counts, n);
        k_hist<<<ge, B, 0, stream>>>(dst, counts, e);
        k_scan<<<1, 1024, 0, stream>>>(counts, row_ptr, cursor, n);
        k_fill<<<ge, B, 0, stream>>>(src, dst, cursor, edge_src, e);
        k_dinv_fb<<<gn, B, 0, stream>>>(counts, dinv, n);
        k_gather_mlp<<<gn, B, 0, stream>>>(row_ptr, edge_src, x, dinv, W1, b1, W2, ts, n);
        k_gather2<<<gn, B, 0, stream>>>(row_ptr, edge_src, ts, dinv, b2, out, n);
    }
}